// Round 10
// baseline (850.822 us; speedup 1.0000x reference)
//
#include <hip/hip_runtime.h>
#include <hip/hip_bf16.h>
#include <math.h>

// ---------------- problem constants ----------------
#define NB      64          // 2*N_EP batches
#define S_LEN   1024
#define IN_DIM  255
#define D_IN    256         // IN_DIM + T_DIM
#define L_DIM   512
#define K_CLS   10
#define QL_ELEMS (65536L * 512)   // elems of one activation buffer (B1->B2 offset)

#define TILE 64
#define BKK  16

typedef __hip_bfloat16 bf16;
typedef __attribute__((ext_vector_type(8))) short short8;
typedef __attribute__((ext_vector_type(4))) float f32x4;

__device__ __forceinline__ float u2f(unsigned short u) {
    return __uint_as_float(((unsigned int)u) << 16);
}
__device__ __forceinline__ unsigned short f2bu(float x) {
    bf16 b = __float2bfloat16(x);
    return *reinterpret_cast<unsigned short*>(&b);
}

// async global->LDS, 16B per lane; lds dest = wave-uniform base + lane*16
typedef const __attribute__((address_space(1))) unsigned int* gas_t;
typedef __attribute__((address_space(3))) unsigned int* las_t;
__device__ __forceinline__ void gload16(const bf16* g, bf16* l) {
    __builtin_amdgcn_global_load_lds((gas_t)(const void*)g, (las_t)(void*)l, 16, 0, 0);
}

// ---------------- build concatenated X (bf16) ----------------
__global__ __launch_bounds__(256) void build_xb(const float* __restrict__ xs,
                                                const float* __restrict__ ys,
                                                bf16* __restrict__ X) {
    long i = (long)blockIdx.x * 256 + threadIdx.x;          // over 65536*256
    long m = i >> 8;
    int  kk = (int)(i & 255);
    float v = (kk < IN_DIM) ? xs[m * IN_DIM + kk] : ys[m];
    X[i] = __float2bfloat16(v);
}

// ---------------- weight transposes + bias concats, one dispatch ----------------
struct TW {
    const float* s0; const float* s1; const float* s2; const float* s3; const float* s4;
    bf16* d0; bf16* d1; bf16* d2; bf16* d3; bf16* d4;
    const float* bq1; const float* bk1; const float* bv1;
    const float* bq2; const float* bk2;
    float* biasQKV;   // [1536]
    float* bias2;     // [1024]
};
__global__ __launch_bounds__(256) void transpose_all(TW tw) {
    int i = blockIdx.x * 256 + threadIdx.x;    // 0 .. 920064
    if (i < 917504) {
        const float* S; bf16* D; int K, j;
        if (i < 131072)      { S = tw.s0; D = tw.d0; K = 256; j = i; }
        else if (i < 262144) { S = tw.s1; D = tw.d1; K = 256; j = i - 131072; }
        else if (i < 393216) { S = tw.s2; D = tw.d2; K = 256; j = i - 262144; }
        else if (i < 655360) { S = tw.s3; D = tw.d3; K = 512; j = i - 393216; }
        else                 { S = tw.s4; D = tw.d4; K = 512; j = i - 655360; }
        int n = j / K, k = j - n * K;
        D[j] = __float2bfloat16(S[(long)k * 512 + n]);
    } else if (i < 919040) {
        int j = i - 917504;        // 0..1535
        float v = (j < 512) ? tw.bq1[j] : (j < 1024 ? tw.bk1[j - 512] : tw.bv1[j - 1024]);
        tw.biasQKV[j] = v;
    } else if (i < 920064) {
        int j = i - 919040;        // 0..1023
        tw.bias2[j] = (j < 512) ? tw.bq2[j] : tw.bk2[j - 512];
    }
}

// ---------------- MFMA GEMM: C = alpha * A @ B^T (+bias) (relu) ----------------
// A: [M][K] bf16 row-major. B: [N][K] bf16 row-major. C bf16.
// TRANSC: C[col][row] with ldc (=M).
// EXPO: e = exp(min(alpha*acc,80)); partial row sums -> ps[(bz*16+bx*2+wn)*1024+row];
//       C written only if WRITEC.
// RSCALE: rows scaled by 1/rowsum, with rowsum = sum of the 16 ps partials for the
//         row, computed inline into LDS (ps is INPUT here; M must be 1024).
// FUSE=1: QKV1 fused epilogue. N=1536 segments of 512: seg0->C, seg1->C+QL, both
//         normal ldc=512; seg2->C+2QL TRANSPOSED (ldc=1024). bias indexed by global col.
// FUSE=2: QK2 fused: N=1024, seg0->C, seg1->C+QL, normal ldc=512.
// 128x128 tile, 4 waves (each 64x64 = 4x4 frags of 16x16), BK=32,
// 2-phase double-buffered LDS: stage(t+1) issued before compute(t), one barrier/K-step.
// Grid is XCD-chunk-swizzled (bijective, requires nwg%8==0 else identity).
template <bool TRANSC, bool RELU, bool HASBIAS, bool EXPO, bool RSCALE, bool WRITEC, int FUSE>
__global__ __launch_bounds__(256) void gemm_mfma(const bf16* __restrict__ A,
                                                 const bf16* __restrict__ B,
                                                 const float* __restrict__ bias,
                                                 bf16* __restrict__ C,
                                                 int K, long sA, long sB, long sC,
                                                 int ldc, float alpha,
                                                 float* __restrict__ ps,
                                                 const float* __restrict__ rsinv_unused) {
    __shared__ bf16 As[2][128 * 32];
    __shared__ bf16 Bs[2][128 * 32];
    __shared__ float rsl[128];          // used only when RSCALE

    // XCD-aware bijective swizzle over the whole 3D grid
    const int gx = gridDim.x, gy = gridDim.y;
    const int nwg = gx * gy * gridDim.z;
    int orig = blockIdx.x + gx * (blockIdx.y + gy * blockIdx.z);
    int id = ((nwg & 7) == 0) ? ((orig & 7) * (nwg >> 3) + (orig >> 3)) : orig;
    const int bx = id % gx;
    const int byz = id / gx;
    const int by = byz % gy;
    const int bz = byz / gy;

    A += (long)bz * sA;
    B += (long)bz * sB;
    C += (long)bz * sC;
    const int bm = by * 128;
    const int bn = bx * 128;
    const int t  = threadIdx.x;
    const int ln = t & 63;
    const int wv = t >> 6;          // wave 0..3
    const int wm = wv >> 1;         // 2x2 wave grid over 128x128
    const int wn = wv & 1;

    const bf16* gA = A + (long)(bm + (t >> 2)) * K + (t & 3) * 8;
    const bf16* gB = B + (long)(bn + (t >> 2)) * K + (t & 3) * 8;
    const int wb = wv * 512;        // wave-uniform LDS base (1024 B per wave)

    // inline rsinv from 16 ps partials (produced by the preceding EXPO dispatch)
    if constexpr (RSCALE) {
        if (t < 128) {
            float s = 0.f;
            #pragma unroll
            for (int cb = 0; cb < 16; ++cb)
                s += ps[((long)bz * 16 + cb) * 1024 + bm + t];
            rsl[t] = 1.f / s;
        }
    }

    f32x4 acc[4][4];
    #pragma unroll
    for (int i = 0; i < 4; ++i)
        #pragma unroll
        for (int j = 0; j < 4; ++j)
            #pragma unroll
            for (int q = 0; q < 4; ++q) acc[i][j][q] = 0.f;

    const int ro = ln & 15;
    const int ko = (ln >> 4) * 8;

    auto stage = [&](int buf, int k0) {
        gload16(gA + k0,          As[buf] + wb);
        gload16(gA + 64 * K + k0, As[buf] + wb + 2048);
        gload16(gB + k0,          Bs[buf] + wb);
        gload16(gB + 64 * K + k0, Bs[buf] + wb + 2048);
    };

    const int nt = K >> 5;
    stage(0, 0);
    __syncthreads();

    for (int tt = 0; tt < nt; ++tt) {
        const int cur = tt & 1;
        if (tt + 1 < nt) stage(cur ^ 1, (tt + 1) << 5);   // prefetch under compute

        short8 af[4], bg[4];
        #pragma unroll
        for (int i = 0; i < 4; ++i) {
            af[i] = *(const short8*)(As[cur] + (wm * 64 + i * 16 + ro) * 32 + ko);
            bg[i] = *(const short8*)(Bs[cur] + (wn * 64 + i * 16 + ro) * 32 + ko);
        }
        #pragma unroll
        for (int i = 0; i < 4; ++i)
            #pragma unroll
            for (int j = 0; j < 4; ++j)
                acc[i][j] = __builtin_amdgcn_mfma_f32_16x16x32_bf16(af[i], bg[j], acc[i][j], 0, 0, 0);
        __syncthreads();   // drains prefetch vmcnt + orders buffer reuse
    }

    // C/D layout: col = lane&15, row = (lane>>4)*4 + reg
    const int r0 = bm + wm * 64 + (ln >> 4) * 4;
    const int c0 = bn + wn * 64 + (ln & 15);

    if constexpr (FUSE > 0) {
        const int seg = bn >> 9;                 // uniform per block (128 | 512)
        if (FUSE == 1 && seg == 2) {
            // V1^T segment: C[col'][row], ldc 1024
            bf16* Cs = C + 2 * QL_ELEMS;
            #pragma unroll
            for (int i = 0; i < 4; ++i) {
                const int rowb = r0 + i * 16;
                #pragma unroll
                for (int j = 0; j < 4; ++j) {
                    const int col = c0 + j * 16;
                    const float bi = bias[col];
                    ushort4 o;
                    o.x = f2bu(acc[i][j][0] + bi);
                    o.y = f2bu(acc[i][j][1] + bi);
                    o.z = f2bu(acc[i][j][2] + bi);
                    o.w = f2bu(acc[i][j][3] + bi);
                    *(ushort4*)(Cs + (long)(col - 1024) * 1024 + rowb) = o;
                }
            }
        } else {
            bf16* Cs = C + (long)seg * QL_ELEMS;
            #pragma unroll
            for (int i = 0; i < 4; ++i) {
                #pragma unroll
                for (int j = 0; j < 4; ++j) {
                    const int col = c0 + j * 16;
                    const float bi = bias[col];
                    const int cl = col - seg * 512;
                    #pragma unroll
                    for (int q = 0; q < 4; ++q)
                        Cs[(long)(r0 + i * 16 + q) * 512 + cl] = __float2bfloat16(acc[i][j][q] + bi);
                }
            }
        }
    } else if constexpr (TRANSC) {
        #pragma unroll
        for (int i = 0; i < 4; ++i) {
            const int rowb = r0 + i * 16;
            #pragma unroll
            for (int j = 0; j < 4; ++j) {
                const int col = c0 + j * 16;
                const float bi = HASBIAS ? bias[col] : 0.f;
                ushort4 o;
                float v0 = acc[i][j][0] * alpha + bi;
                float v1 = acc[i][j][1] * alpha + bi;
                float v2 = acc[i][j][2] * alpha + bi;
                float v3 = acc[i][j][3] * alpha + bi;
                if (RELU) { v0 = fmaxf(v0, 0.f); v1 = fmaxf(v1, 0.f); v2 = fmaxf(v2, 0.f); v3 = fmaxf(v3, 0.f); }
                o.x = f2bu(v0); o.y = f2bu(v1); o.z = f2bu(v2); o.w = f2bu(v3);
                *(ushort4*)(C + (long)col * ldc + rowb) = o;
            }
        }
    } else if constexpr (EXPO) {
        float sloc[4][4];
        #pragma unroll
        for (int i = 0; i < 4; ++i)
            #pragma unroll
            for (int q = 0; q < 4; ++q) sloc[i][q] = 0.f;
        #pragma unroll
        for (int i = 0; i < 4; ++i) {
            #pragma unroll
            for (int j = 0; j < 4; ++j) {
                const int col = c0 + j * 16;
                #pragma unroll
                for (int q = 0; q < 4; ++q) {
                    float e = __expf(fminf(acc[i][j][q] * alpha, 80.f));
                    sloc[i][q] += e;
                    if (WRITEC) C[(long)(r0 + i * 16 + q) * ldc + col] = __float2bfloat16(e);
                }
            }
        }
        // reduce partial row sums across the 16 lanes holding one row's columns
        #pragma unroll
        for (int o = 1; o < 16; o <<= 1)
            #pragma unroll
            for (int i = 0; i < 4; ++i)
                #pragma unroll
                for (int q = 0; q < 4; ++q)
                    sloc[i][q] += __shfl_xor(sloc[i][q], o, 64);
        if ((ln & 15) == 0) {
            const int cb = bx * 2 + wn;
            const int rb = bm + wm * 64 + (ln >> 4) * 4;
            #pragma unroll
            for (int i = 0; i < 4; ++i)
                #pragma unroll
                for (int q = 0; q < 4; ++q)
                    ps[((long)bz * 16 + cb) * 1024 + rb + i * 16 + q] = sloc[i][q];
        }
    } else {
        float rsv[4][4];
        if constexpr (RSCALE) {
            const int lr = wm * 64 + (ln >> 4) * 4;       // local row base in tile
            #pragma unroll
            for (int i = 0; i < 4; ++i)
                #pragma unroll
                for (int q = 0; q < 4; ++q)
                    rsv[i][q] = rsl[lr + i * 16 + q];
        }
        #pragma unroll
        for (int i = 0; i < 4; ++i) {
            #pragma unroll
            for (int j = 0; j < 4; ++j) {
                const int col = c0 + j * 16;
                const float bi = HASBIAS ? bias[col] : 0.f;
                #pragma unroll
                for (int q = 0; q < 4; ++q) {
                    float v = acc[i][j][q] * alpha + bi;
                    if (RSCALE) v *= rsv[i][q];
                    if (RELU) v = fmaxf(v, 0.f);
                    C[(long)(r0 + i * 16 + q) * ldc + col] = __float2bfloat16(v);
                }
            }
        }
    }
}

// ---------------- scaled column partial sums of P-tilde chunk ----------------
// wps[((c0*bch+b)*4+z)*1024 + col] = sum_{q in z-chunk of 256} Ptilde[q][col]/rowsum[q]
// rowsum computed inline from the 16 ps partials.
__global__ __launch_bounds__(256) void colsum_part(const bf16* __restrict__ Sc,
                                                   const float* __restrict__ ps,
                                                   float* __restrict__ wps,
                                                   int c0, int bch) {
    const int b = blockIdx.y;                          // 0..bch-1
    const int z = blockIdx.z;                          // q-chunk 0..3
    const int c = blockIdx.x * 256 + threadIdx.x;      // grid.x = 4
    const int t = threadIdx.x;
    __shared__ float rsl[256];
    {
        const int row = z * 256 + t;
        float s = 0.f;
        #pragma unroll
        for (int cb = 0; cb < 16; ++cb) s += ps[((long)b * 16 + cb) * 1024 + row];
        rsl[t] = 1.f / s;
    }
    __syncthreads();
    const bf16* p = Sc + (long)b * (S_LEN * S_LEN) + (long)z * 256 * S_LEN + c;
    float acc = 0.f;
    for (int q = 0; q < 256; ++q) acc += __bfloat162float(p[(long)q * S_LEN]) * rsl[q];
    wps[(((long)c0 * bch + b) * 4 + z) * 1024 + c] = acc;
}

// ---------------- w = sum of 4 col partials ----------------
__global__ __launch_bounds__(256) void colsum_red4(const float* __restrict__ wps,
                                                   float* __restrict__ w, int n) {
    int i = blockIdx.x * 256 + threadIdx.x;
    if (i >= n) return;
    const int b = i >> 10, col = i & 1023;
    w[i] = wps[((long)b * 4 + 0) * 1024 + col] + wps[((long)b * 4 + 1) * 1024 + col]
         + wps[((long)b * 4 + 2) * 1024 + col] + wps[((long)b * 4 + 3) * 1024 + col];
}

// ---------------- tiny fp32 tiled GEMM (tail, M=64) ----------------
template <bool RELU>
__global__ __launch_bounds__(256) void gemm_f32s(const float* __restrict__ A,
                                                 const float* __restrict__ B,
                                                 const float* __restrict__ bias,
                                                 float* __restrict__ C,
                                                 int M, int N, int K) {
    __shared__ float As[BKK][TILE + 1];
    __shared__ float Bs[BKK][TILE + 1];
    const int bm = blockIdx.y * TILE;
    const int bn = blockIdx.x * TILE;
    const int t  = threadIdx.x;
    const int tx = t & 15, ty = t >> 4;
    float acc[4][4] = {};
    for (int k0 = 0; k0 < K; k0 += BKK) {
        {
            int m  = t >> 2;
            int kq = (t & 3) * 4;
            const float4 av = *(const float4*)(A + (long)(bm + m) * K + k0 + kq);
            As[kq + 0][m] = av.x; As[kq + 1][m] = av.y;
            As[kq + 2][m] = av.z; As[kq + 3][m] = av.w;
        }
        {
            int k  = t >> 4;
            int nq = (t & 15) * 4;
            const float4 bv = *(const float4*)(B + (long)(k0 + k) * N + bn + nq);
            Bs[k][nq + 0] = bv.x; Bs[k][nq + 1] = bv.y;
            Bs[k][nq + 2] = bv.z; Bs[k][nq + 3] = bv.w;
        }
        __syncthreads();
        #pragma unroll
        for (int k = 0; k < BKK; ++k) {
            float a[4], bb[4];
            #pragma unroll
            for (int i = 0; i < 4; ++i) a[i] = As[k][ty * 4 + i];
            #pragma unroll
            for (int j = 0; j < 4; ++j) bb[j] = Bs[k][tx * 4 + j];
            #pragma unroll
            for (int i = 0; i < 4; ++i)
                #pragma unroll
                for (int j = 0; j < 4; ++j)
                    acc[i][j] = fmaf(a[i], bb[j], acc[i][j]);
        }
        __syncthreads();
    }
    #pragma unroll
    for (int i = 0; i < 4; ++i) {
        const int row  = bm + ty * 4 + i;
        const int col0 = bn + tx * 4;
        #pragma unroll
        for (int j = 0; j < 4; ++j) {
            float x = acc[i][j] + bias[col0 + j];
            if (RELU) x = fmaxf(x, 0.f);
            C[(long)row * N + col0 + j] = x;
        }
    }
}

// ---------------- u partials over q-chunks ----------------
__global__ __launch_bounds__(256) void pool_u_part(const bf16* __restrict__ h,
                                                   const float* __restrict__ w,
                                                   float* __restrict__ up) {
    const int b  = blockIdx.x;          // 64 batches
    const int qq = blockIdx.y;          // 4 q-chunks of 256
    const int t  = threadIdx.x;         // owns d = 2t, 2t+1
    __shared__ float wl[256];
    wl[t] = w[b * S_LEN + qq * 256 + t];
    __syncthreads();
    const bf16* hp = h + (long)b * S_LEN * L_DIM + (long)qq * 256 * L_DIM;
    float a0 = 0.f, a1 = 0.f;
    for (int q = 0; q < 256; ++q) {
        ushort2 uv = *(const ushort2*)(hp + (long)q * L_DIM + t * 2);
        float ww = wl[q];
        a0 = fmaf(ww, u2f(uv.x), a0);
        a1 = fmaf(ww, u2f(uv.y), a1);
    }
    up[((long)(b * 4 + qq)) * L_DIM + t * 2 + 0] = a0;
    up[((long)(b * 4 + qq)) * L_DIM + t * 2 + 1] = a1;
}

__global__ __launch_bounds__(256) void pool_u_red(const float* __restrict__ up,
                                                  float* __restrict__ u) {
    int i = blockIdx.x * 256 + threadIdx.x;   // 64*512
    if (i >= NB * L_DIM) return;
    int b = i >> 9, d = i & 511;
    float s = up[((long)(b * 4 + 0)) * L_DIM + d] + up[((long)(b * 4 + 1)) * L_DIM + d]
            + up[((long)(b * 4 + 2)) * L_DIM + d] + up[((long)(b * 4 + 3)) * L_DIM + d];
    u[i] = s * (1.f / (float)S_LEN);
}

// ---------------- log_softmax over groups of 10 ----------------
__global__ __launch_bounds__(256) void log_softmax10(const float* __restrict__ logits,
                                                     float* __restrict__ out) {
    const int t = blockIdx.x * 256 + threadIdx.x;     // 64*512 groups
    if (t >= NB * L_DIM) return;
    const float* p = logits + (long)t * K_CLS;
    float v[K_CLS], m = -INFINITY;
    #pragma unroll
    for (int k = 0; k < K_CLS; ++k) { v[k] = p[k]; m = fmaxf(m, v[k]); }
    float s = 0.f;
    #pragma unroll
    for (int k = 0; k < K_CLS; ++k) s += __expf(v[k] - m);
    const float lse = m + logf(s);
    float* o = out + (long)t * K_CLS;
    #pragma unroll
    for (int k = 0; k < K_CLS; ++k) o[k] = v[k] - lse;
}

// ---------------- host launch ----------------
extern "C" void kernel_launch(void* const* d_in, const int* in_sizes, int n_in,
                              void* d_out, int out_size, void* d_ws, size_t ws_size,
                              hipStream_t stream) {
    const float* xs  = (const float*)d_in[0];
    const float* ys  = (const float*)d_in[1];
    const float* Wq1 = (const float*)d_in[2];  const float* bq1 = (const float*)d_in[3];
    const float* Wk1 = (const float*)d_in[4];  const float* bk1 = (const float*)d_in[5];
    const float* Wv1 = (const float*)d_in[6];  const float* bv1 = (const float*)d_in[7];
    const float* Wq2 = (const float*)d_in[8];  const float* bq2 = (const float*)d_in[9];
    const float* Wk2 = (const float*)d_in[10]; const float* bk2 = (const float*)d_in[11];
    const float* Wv2 = (const float*)d_in[12]; const float* bv2 = (const float*)d_in[13];
    const float* We  = (const float*)d_in[14]; const float* be  = (const float*)d_in[15];
    float* out = (float*)d_out;

    const long M  = (long)NB * S_LEN;        // 65536
    const long QL = M * L_DIM;               // 33.5M elems (== QL_ELEMS)
    const long SL = (long)S_LEN * L_DIM;     // per-batch activation stride (also V1T stride)
    const long SS = (long)S_LEN * S_LEN;     // per-batch score stride

    // ---- workspace layout (bf16 first, then fp32) ----
    bf16* Xb  = (bf16*)d_ws;                 // 33.5 MB
    bf16* B1  = Xb + M * D_IN;               // 67.1 MB  (q1 -> h)
    bf16* B2  = B1 + QL;                     // 67.1 MB  (k1 -> q2)
    bf16* B3  = B2 + QL;                     // 67.1 MB  (v1T -> k2)
    bf16* WTb = B3 + QL;                     // 1.8 MB: [Wq1T;Wk1T;Wv1T][Wq2T;Wk2T] contiguous
    bf16* Wq1T = WTb;                        // fused QKV1 B-matrix = WTb as [1536][256]
    bf16* Wk1T = Wq1T + L_DIM * D_IN;
    bf16* Wv1T = Wk1T + L_DIM * D_IN;
    bf16* Wq2T = Wv1T + L_DIM * D_IN;        // fused QK2 B-matrix = Wq2T as [1024][512]
    bf16* Wk2T = Wq2T + L_DIM * L_DIM;
    bf16* Scb  = Wk2T + L_DIM * L_DIM;       // BCH1 * 2 MB score chunk (both layers)

    // chunk = 16 batches -> 32MB Ptilde chunk, stays L3-resident (round-7/9 proven)
    const size_t base_b = (size_t)((char*)Scb - (char*)d_ws);
    const size_t f32_b  = (size_t)(M + 2 * NB * L_DIM + NB * L_DIM * K_CLS
                                   + 64 * 16 * 1024 + 4 * NB * L_DIM
                                   + 64 * 4 * 1024 + 1536 + 1024) * 4 + 256;
    int BCH1 = 16;
    while (BCH1 > 8 && base_b + (size_t)BCH1 * SS * 2 + f32_b > ws_size) BCH1 >>= 1;

    float* w       = (float*)(Scb + (long)BCH1 * SS);  // 64*1024 col sums
    float* u       = w   + M / S_LEN * 1024;           // = w + 65536
    float* phi     = u   + NB * L_DIM;
    float* lg      = phi + NB * L_DIM;
    float* ps      = lg  + NB * L_DIM * K_CLS;         // 16 row-sum partials x 64 batches
    float* up      = ps  + 64 * 16 * 1024;             // pool partials 64x4x512
    float* wps     = up  + 4 * NB * L_DIM;             // 4 col partials x 64 batches
    float* biasQKV = wps + 64 * 4 * 1024;              // 1536
    float* bias2   = biasQKV + 1536;                   // 1024

    const float inv_sqrt_L = 0.044194173824159216f;  // 1/sqrt(512)

    // 0) X = concat(x_sets, y_sets) -> bf16 ; transpose weights + concat biases
    build_xb<<<dim3((unsigned)(M * D_IN / 256)), 256, 0, stream>>>(xs, ys, Xb);
    {
        TW tw { Wq1, Wk1, Wv1, Wq2, Wk2, Wq1T, Wk1T, Wv1T, Wq2T, Wk2T,
                bq1, bk1, bv1, bq2, bk2, biasQKV, bias2 };
        transpose_all<<<dim3(3595), 256, 0, stream>>>(tw);
    }

    // 1) layer-1 QKV fused (N=1536): q1->B1, k1->B2, v1T->B3 (seg2 transposed)
    {
        dim3 g(1536 / 128, S_LEN / 128, NB);
        gemm_mfma<false, false, true, false, false, true, 1><<<g, 256, 0, stream>>>(
            Xb, WTb, biasQKV, B1, D_IN, (long)S_LEN * D_IN, 0, SL, L_DIM, 1.f, nullptr, nullptr);
    }
    // 2) layer-1 attention, chunked (32MB L3-resident Ptilde chunk):
    //    Ptilde=exp(scores)+ps -> h = relu((P@v)/rowsum) -> B1  (rsinv inline from ps)
    for (int c = 0; c < NB / BCH1; ++c) {
        const long aoff = (long)c * BCH1 * SL;
        float* psc = ps + (long)c * BCH1 * 16 * 1024;
        dim3 gs(S_LEN / 128, S_LEN / 128, BCH1);
        gemm_mfma<false, false, false, true, false, true, 0><<<gs, 256, 0, stream>>>(
            B1 + aoff, B2 + aoff, nullptr, Scb, L_DIM, SL, SL, SS, S_LEN, inv_sqrt_L, psc, nullptr);
        dim3 gp(L_DIM / 128, S_LEN / 128, BCH1);
        gemm_mfma<false, true, false, false, true, true, 0><<<gp, 256, 0, stream>>>(
            Scb, B3 + aoff, nullptr, B1 + aoff, S_LEN, SS, SL, SL, L_DIM, 1.f, psc, nullptr);
    }
    // 3) layer-2 Q,K fused from h (B1): q2->B2, k2->B3 (v2 eliminated by linearity)
    {
        dim3 g(1024 / 128, S_LEN / 128, NB);
        gemm_mfma<false, false, true, false, false, true, 2><<<g, 256, 0, stream>>>(
            B1, Wq2T, bias2, B2, L_DIM, SL, 0, SL, L_DIM, 1.f, nullptr, nullptr);
    }
    // 4) layer-2 attention, same chunked-materialized pattern:
    //    Ptilde=exp(scores)+ps -> col partial sums scaled by 1/rowsum (inline)
    for (int c = 0; c < NB / BCH1; ++c) {
        const long aoff = (long)c * BCH1 * SL;
        float* psc = ps + (long)c * BCH1 * 16 * 1024;
        dim3 gs(S_LEN / 128, S_LEN / 128, BCH1);
        gemm_mfma<false, false, false, true, false, true, 0><<<gs, 256, 0, stream>>>(
            B2 + aoff, B3 + aoff, nullptr, Scb, L_DIM, SL, SL, SS, S_LEN, inv_sqrt_L, psc, nullptr);
        colsum_part<<<dim3(S_LEN / 256, BCH1, 4), 256, 0, stream>>>(Scb, psc, wps, c, BCH1);
    }
    colsum_red4<<<dim3((unsigned)(NB * S_LEN / 256)), 256, 0, stream>>>(wps, w, NB * S_LEN);
    // 5) u = (w/S) @ h  (parallel partials + reduce)
    pool_u_part<<<dim3(NB, 4), 256, 0, stream>>>(B1, w, up);
    pool_u_red<<<dim3(NB * L_DIM / 256), 256, 0, stream>>>(up, u);
    // 6) phi = relu(u @ Wv2 + bv2)   (64 x 512, K=512)
    gemm_f32s<true><<<dim3(L_DIM / TILE, 1), 256, 0, stream>>>(u, Wv2, bv2, phi, NB, L_DIM, L_DIM);
    // 7) logits = phi @ We + be      (64 x 5120, K=512)
    gemm_f32s<false><<<dim3((L_DIM * K_CLS) / TILE, 1), 256, 0, stream>>>(phi, We, be, lg, NB, L_DIM * K_CLS, L_DIM);
    // 8) log_softmax over K=10
    log_softmax10<<<dim3((NB * L_DIM + 255) / 256), 256, 0, stream>>>(lg, out);
}

// Round 11
// 804.394 us; speedup vs baseline: 1.0577x; 1.0577x over previous
//
#include <hip/hip_runtime.h>
#include <hip/hip_bf16.h>
#include <math.h>

// ---------------- problem constants ----------------
#define NB      64          // 2*N_EP batches
#define S_LEN   1024
#define IN_DIM  255
#define D_IN    256         // IN_DIM + T_DIM
#define L_DIM   512
#define K_CLS   10
#define QL_ELEMS (65536L * 512)   // elems of one activation buffer (B1->B2 offset)

#define TILE 64
#define BKK  16

typedef __hip_bfloat16 bf16;
typedef __attribute__((ext_vector_type(8))) short short8;
typedef __attribute__((ext_vector_type(4))) float f32x4;

__device__ __forceinline__ float u2f(unsigned short u) {
    return __uint_as_float(((unsigned int)u) << 16);
}
__device__ __forceinline__ unsigned short f2bu(float x) {
    bf16 b = __float2bfloat16(x);
    return *reinterpret_cast<unsigned short*>(&b);
}

// async global->LDS, 16B per lane; lds dest = wave-uniform base + lane*16
typedef const __attribute__((address_space(1))) unsigned int* gas_t;
typedef __attribute__((address_space(3))) unsigned int* las_t;
__device__ __forceinline__ void gload16(const bf16* g, bf16* l) {
    __builtin_amdgcn_global_load_lds((gas_t)(const void*)g, (las_t)(void*)l, 16, 0, 0);
}

// ---------------- fused: build X (bf16) + weight transposes + bias concats ----------------
struct TW {
    const float* xs; const float* ys; bf16* X;
    const float* s0; const float* s1; const float* s2; const float* s3; const float* s4;
    bf16* d0; bf16* d1; bf16* d2; bf16* d3; bf16* d4;
    const float* bq1; const float* bk1; const float* bv1;
    const float* bq2; const float* bk2;
    float* biasQKV;   // [1536]
    float* bias2;     // [1024]
};
#define X_ELEMS 16777216L
__global__ __launch_bounds__(256) void prep_all(TW tw) {
    long i = (long)blockIdx.x * 256 + threadIdx.x;
    if (i < X_ELEMS) {
        long m = i >> 8;
        int  kk = (int)(i & 255);
        float v = (kk < IN_DIM) ? tw.xs[m * IN_DIM + kk] : tw.ys[m];
        tw.X[i] = __float2bfloat16(v);
        return;
    }
    int j0 = (int)(i - X_ELEMS);     // 0 .. 920063
    if (j0 < 917504) {
        const float* S; bf16* D; int K, j;
        if (j0 < 131072)      { S = tw.s0; D = tw.d0; K = 256; j = j0; }
        else if (j0 < 262144) { S = tw.s1; D = tw.d1; K = 256; j = j0 - 131072; }
        else if (j0 < 393216) { S = tw.s2; D = tw.d2; K = 256; j = j0 - 262144; }
        else if (j0 < 655360) { S = tw.s3; D = tw.d3; K = 512; j = j0 - 393216; }
        else                  { S = tw.s4; D = tw.d4; K = 512; j = j0 - 655360; }
        int n = j / K, k = j - n * K;
        D[j] = __float2bfloat16(S[(long)k * 512 + n]);
    } else if (j0 < 919040) {
        int j = j0 - 917504;        // 0..1535
        float v = (j < 512) ? tw.bq1[j] : (j < 1024 ? tw.bk1[j - 512] : tw.bv1[j - 1024]);
        tw.biasQKV[j] = v;
    } else if (j0 < 920064) {
        int j = j0 - 919040;        // 0..1023
        tw.bias2[j] = (j < 512) ? tw.bq2[j] : tw.bk2[j - 512];
    }
}

// ---------------- MFMA GEMM: C = alpha * A @ B^T (+bias) (relu) ----------------
// A: [M][K] bf16 row-major. B: [N][K] bf16 row-major. C bf16.
// EXPO: e = exp(min(alpha*acc,80)); partial row sums -> ps[(bz*16+bx*2+wn)*1024+row];
//       C written only if WRITEC.
// RSCALE: rows scaled by 1/rowsum; rowsum = sum of 16 psIn partials, inline in LDS.
// WCOL: no C write; col partials sum_rows exp(alpha*acc)/rowsum[row] (rowsum inline
//       from psIn) -> ps[(bz*16 + by*2+wm)*1024 + col].
// FUSE=1: QKV1 fused epilogue (N=1536; seg0/1 normal ldc=512, seg2 transposed ldc=1024).
// FUSE=2: QK2 fused (N=1024; seg0->C, seg1->C+QL).
// 128x128 tile, 4 waves, BK=32, 2-phase dbuf LDS, XCD-chunk-swizzled grid.
template <bool RELU, bool HASBIAS, bool EXPO, bool RSCALE, bool WRITEC, int FUSE, bool WCOL>
__global__ __launch_bounds__(256) void gemm_mfma(const bf16* __restrict__ A,
                                                 const bf16* __restrict__ B,
                                                 const float* __restrict__ bias,
                                                 bf16* __restrict__ C,
                                                 int K, long sA, long sB, long sC,
                                                 int ldc, float alpha,
                                                 float* __restrict__ ps,
                                                 const float* __restrict__ psIn) {
    __shared__ bf16 As[2][128 * 32];
    __shared__ bf16 Bs[2][128 * 32];
    __shared__ float rsl[128];          // used only when RSCALE || WCOL

    // XCD-aware bijective swizzle over the whole 3D grid
    const int gx = gridDim.x, gy = gridDim.y;
    const int nwg = gx * gy * gridDim.z;
    int orig = blockIdx.x + gx * (blockIdx.y + gy * blockIdx.z);
    int id = ((nwg & 7) == 0) ? ((orig & 7) * (nwg >> 3) + (orig >> 3)) : orig;
    const int bx = id % gx;
    const int byz = id / gx;
    const int by = byz % gy;
    const int bz = byz / gy;

    A += (long)bz * sA;
    B += (long)bz * sB;
    C += (long)bz * sC;
    const int bm = by * 128;
    const int bn = bx * 128;
    const int t  = threadIdx.x;
    const int ln = t & 63;
    const int wv = t >> 6;          // wave 0..3
    const int wm = wv >> 1;         // 2x2 wave grid over 128x128
    const int wn = wv & 1;

    const bf16* gA = A + (long)(bm + (t >> 2)) * K + (t & 3) * 8;
    const bf16* gB = B + (long)(bn + (t >> 2)) * K + (t & 3) * 8;
    const int wb = wv * 512;        // wave-uniform LDS base (1024 B per wave)

    // inline 1/rowsum from 16 ps partials (produced by the preceding EXPO dispatch)
    if constexpr (RSCALE || WCOL) {
        if (t < 128) {
            float s = 0.f;
            #pragma unroll
            for (int cb = 0; cb < 16; ++cb)
                s += psIn[((long)bz * 16 + cb) * 1024 + bm + t];
            rsl[t] = 1.f / s;
        }
    }

    f32x4 acc[4][4];
    #pragma unroll
    for (int i = 0; i < 4; ++i)
        #pragma unroll
        for (int j = 0; j < 4; ++j)
            #pragma unroll
            for (int q = 0; q < 4; ++q) acc[i][j][q] = 0.f;

    const int ro = ln & 15;
    const int ko = (ln >> 4) * 8;

    auto stage = [&](int buf, int k0) {
        gload16(gA + k0,          As[buf] + wb);
        gload16(gA + 64 * K + k0, As[buf] + wb + 2048);
        gload16(gB + k0,          Bs[buf] + wb);
        gload16(gB + 64 * K + k0, Bs[buf] + wb + 2048);
    };

    const int nt = K >> 5;
    stage(0, 0);
    __syncthreads();

    for (int tt = 0; tt < nt; ++tt) {
        const int cur = tt & 1;
        if (tt + 1 < nt) stage(cur ^ 1, (tt + 1) << 5);   // prefetch under compute

        short8 af[4], bg[4];
        #pragma unroll
        for (int i = 0; i < 4; ++i) {
            af[i] = *(const short8*)(As[cur] + (wm * 64 + i * 16 + ro) * 32 + ko);
            bg[i] = *(const short8*)(Bs[cur] + (wn * 64 + i * 16 + ro) * 32 + ko);
        }
        #pragma unroll
        for (int i = 0; i < 4; ++i)
            #pragma unroll
            for (int j = 0; j < 4; ++j)
                acc[i][j] = __builtin_amdgcn_mfma_f32_16x16x32_bf16(af[i], bg[j], acc[i][j], 0, 0, 0);
        __syncthreads();   // drains prefetch vmcnt + orders buffer reuse
    }

    // C/D layout: col = lane&15, row = (lane>>4)*4 + reg
    const int r0 = bm + wm * 64 + (ln >> 4) * 4;
    const int c0 = bn + wn * 64 + (ln & 15);

    if constexpr (FUSE > 0) {
        const int seg = bn >> 9;                 // uniform per block (128 | 512)
        if (FUSE == 1 && seg == 2) {
            // V1^T segment: C[col'][row], ldc 1024
            bf16* Cs = C + 2 * QL_ELEMS;
            #pragma unroll
            for (int i = 0; i < 4; ++i) {
                const int rowb = r0 + i * 16;
                #pragma unroll
                for (int j = 0; j < 4; ++j) {
                    const int col = c0 + j * 16;
                    const float bi = bias[col];
                    ushort4 o;
                    o.x = f2bu(acc[i][j][0] + bi);
                    o.y = f2bu(acc[i][j][1] + bi);
                    o.z = f2bu(acc[i][j][2] + bi);
                    o.w = f2bu(acc[i][j][3] + bi);
                    *(ushort4*)(Cs + (long)(col - 1024) * 1024 + rowb) = o;
                }
            }
        } else {
            bf16* Cs = C + (long)seg * QL_ELEMS;
            #pragma unroll
            for (int i = 0; i < 4; ++i) {
                #pragma unroll
                for (int j = 0; j < 4; ++j) {
                    const int col = c0 + j * 16;
                    const float bi = bias[col];
                    const int cl = col - seg * 512;
                    #pragma unroll
                    for (int q = 0; q < 4; ++q)
                        Cs[(long)(r0 + i * 16 + q) * 512 + cl] = __float2bfloat16(acc[i][j][q] + bi);
                }
            }
        }
    } else if constexpr (EXPO) {
        float sloc[4][4];
        #pragma unroll
        for (int i = 0; i < 4; ++i)
            #pragma unroll
            for (int q = 0; q < 4; ++q) sloc[i][q] = 0.f;
        #pragma unroll
        for (int i = 0; i < 4; ++i) {
            #pragma unroll
            for (int j = 0; j < 4; ++j) {
                const int col = c0 + j * 16;
                #pragma unroll
                for (int q = 0; q < 4; ++q) {
                    float e = __expf(fminf(acc[i][j][q] * alpha, 80.f));
                    sloc[i][q] += e;
                    if (WRITEC) C[(long)(r0 + i * 16 + q) * ldc + col] = __float2bfloat16(e);
                }
            }
        }
        // reduce partial row sums across the 16 lanes holding one row's columns
        #pragma unroll
        for (int o = 1; o < 16; o <<= 1)
            #pragma unroll
            for (int i = 0; i < 4; ++i)
                #pragma unroll
                for (int q = 0; q < 4; ++q)
                    sloc[i][q] += __shfl_xor(sloc[i][q], o, 64);
        if ((ln & 15) == 0) {
            const int cb = bx * 2 + wn;
            const int rb = bm + wm * 64 + (ln >> 4) * 4;
            #pragma unroll
            for (int i = 0; i < 4; ++i)
                #pragma unroll
                for (int q = 0; q < 4; ++q)
                    ps[((long)bz * 16 + cb) * 1024 + rb + i * 16 + q] = sloc[i][q];
        }
    } else if constexpr (WCOL) {
        // col partials of sum_rows exp(alpha*acc)/rowsum[row]  (rowsum inline)
        float rsv[4][4];
        const int lr = wm * 64 + (ln >> 4) * 4;
        #pragma unroll
        for (int i = 0; i < 4; ++i)
            #pragma unroll
            for (int q = 0; q < 4; ++q)
                rsv[i][q] = rsl[lr + i * 16 + q];
        float cs[4];
        #pragma unroll
        for (int j = 0; j < 4; ++j) cs[j] = 0.f;
        #pragma unroll
        for (int i = 0; i < 4; ++i)
            #pragma unroll
            for (int j = 0; j < 4; ++j)
                #pragma unroll
                for (int q = 0; q < 4; ++q)
                    cs[j] += __expf(fminf(acc[i][j][q] * alpha, 80.f)) * rsv[i][q];
        // reduce across the 4 row-groups (lanes 16 apart hold different rows, same col)
        #pragma unroll
        for (int j = 0; j < 4; ++j) {
            cs[j] += __shfl_xor(cs[j], 16, 64);
            cs[j] += __shfl_xor(cs[j], 32, 64);
        }
        if (ln < 16) {
            const int cb = by * 2 + wm;      // 8 row-tiles x 2 wm = 16 partials
            #pragma unroll
            for (int j = 0; j < 4; ++j)
                ps[((long)bz * 16 + cb) * 1024 + (bn + wn * 64 + j * 16 + ln)] = cs[j];
        }
    } else {
        float rsv[4][4];
        if constexpr (RSCALE) {
            const int lr = wm * 64 + (ln >> 4) * 4;       // local row base in tile
            #pragma unroll
            for (int i = 0; i < 4; ++i)
                #pragma unroll
                for (int q = 0; q < 4; ++q)
                    rsv[i][q] = rsl[lr + i * 16 + q];
        }
        #pragma unroll
        for (int i = 0; i < 4; ++i) {
            #pragma unroll
            for (int j = 0; j < 4; ++j) {
                const int col = c0 + j * 16;
                const float bi = HASBIAS ? bias[col] : 0.f;
                #pragma unroll
                for (int q = 0; q < 4; ++q) {
                    float v = acc[i][j][q] * alpha + bi;
                    if (RSCALE) v *= rsv[i][q];
                    if (RELU) v = fmaxf(v, 0.f);
                    C[(long)(r0 + i * 16 + q) * ldc + col] = __float2bfloat16(v);
                }
            }
        }
    }
}

// ---------------- u-partials over q-chunks, w inlined from 16 wps partials ----------------
__global__ __launch_bounds__(256) void pool_u_part(const bf16* __restrict__ h,
                                                   const float* __restrict__ wps,
                                                   float* __restrict__ up) {
    const int b  = blockIdx.x;          // 64 batches
    const int qq = blockIdx.y;          // 4 q-chunks of 256
    const int t  = threadIdx.x;         // owns d = 2t, 2t+1
    __shared__ float wl[256];
    {
        float s = 0.f;
        #pragma unroll
        for (int cb = 0; cb < 16; ++cb)
            s += wps[((long)b * 16 + cb) * 1024 + qq * 256 + t];
        wl[t] = s;
    }
    __syncthreads();
    const bf16* hp = h + (long)b * S_LEN * L_DIM + (long)qq * 256 * L_DIM;
    float a0 = 0.f, a1 = 0.f;
    for (int q = 0; q < 256; ++q) {
        ushort2 uv = *(const ushort2*)(hp + (long)q * L_DIM + t * 2);
        float ww = wl[q];
        a0 = fmaf(ww, u2f(uv.x), a0);
        a1 = fmaf(ww, u2f(uv.y), a1);
    }
    up[((long)(b * 4 + qq)) * L_DIM + t * 2 + 0] = a0;
    up[((long)(b * 4 + qq)) * L_DIM + t * 2 + 1] = a1;
}

// ---------------- phi = relu((up-reduced/S) @ Wv2 + bv2), M=64 ----------------
__global__ __launch_bounds__(256) void gemm_phi(const float* __restrict__ up,
                                                const float* __restrict__ B,
                                                const float* __restrict__ bias,
                                                float* __restrict__ C) {
    __shared__ float As[BKK][TILE + 1];
    __shared__ float Bs[BKK][TILE + 1];
    const int bn = blockIdx.x * TILE;
    const int t  = threadIdx.x;
    const int tx = t & 15, ty = t >> 4;
    float acc[4][4] = {};
    for (int k0 = 0; k0 < L_DIM; k0 += BKK) {
        {
            int m  = t >> 2;             // batch 0..63
            int kq = (t & 3) * 4;
            const float* pb = up + (long)m * 4 * L_DIM + k0 + kq;
            float4 p0 = *(const float4*)(pb);
            float4 p1 = *(const float4*)(pb + L_DIM);
            float4 p2 = *(const float4*)(pb + 2 * L_DIM);
            float4 p3 = *(const float4*)(pb + 3 * L_DIM);
            const float sc = 1.f / (float)S_LEN;
            As[kq + 0][m] = (p0.x + p1.x + p2.x + p3.x) * sc;
            As[kq + 1][m] = (p0.y + p1.y + p2.y + p3.y) * sc;
            As[kq + 2][m] = (p0.z + p1.z + p2.z + p3.z) * sc;
            As[kq + 3][m] = (p0.w + p1.w + p2.w + p3.w) * sc;
        }
        {
            int k  = t >> 4;
            int nq = (t & 15) * 4;
            const float4 bv = *(const float4*)(B + (long)(k0 + k) * L_DIM + bn + nq);
            Bs[k][nq + 0] = bv.x; Bs[k][nq + 1] = bv.y;
            Bs[k][nq + 2] = bv.z; Bs[k][nq + 3] = bv.w;
        }
        __syncthreads();
        #pragma unroll
        for (int k = 0; k < BKK; ++k) {
            float a[4], bb[4];
            #pragma unroll
            for (int i = 0; i < 4; ++i) a[i] = As[k][ty * 4 + i];
            #pragma unroll
            for (int j = 0; j < 4; ++j) bb[j] = Bs[k][tx * 4 + j];
            #pragma unroll
            for (int i = 0; i < 4; ++i)
                #pragma unroll
                for (int j = 0; j < 4; ++j)
                    acc[i][j] = fmaf(a[i], bb[j], acc[i][j]);
        }
        __syncthreads();
    }
    #pragma unroll
    for (int i = 0; i < 4; ++i) {
        const int row  = ty * 4 + i;
        const int col0 = bn + tx * 4;
        #pragma unroll
        for (int j = 0; j < 4; ++j) {
            float x = fmaxf(acc[i][j] + bias[col0 + j], 0.f);
            C[(long)row * L_DIM + col0 + j] = x;
        }
    }
}

// ---------------- tiny fp32 tiled GEMM (logits, M=64) ----------------
__global__ __launch_bounds__(256) void gemm_f32s(const float* __restrict__ A,
                                                 const float* __restrict__ B,
                                                 const float* __restrict__ bias,
                                                 float* __restrict__ C,
                                                 int M, int N, int K) {
    __shared__ float As[BKK][TILE + 1];
    __shared__ float Bs[BKK][TILE + 1];
    const int bm = blockIdx.y * TILE;
    const int bn = blockIdx.x * TILE;
    const int t  = threadIdx.x;
    const int tx = t & 15, ty = t >> 4;
    float acc[4][4] = {};
    for (int k0 = 0; k0 < K; k0 += BKK) {
        {
            int m  = t >> 2;
            int kq = (t & 3) * 4;
            const float4 av = *(const float4*)(A + (long)(bm + m) * K + k0 + kq);
            As[kq + 0][m] = av.x; As[kq + 1][m] = av.y;
            As[kq + 2][m] = av.z; As[kq + 3][m] = av.w;
        }
        {
            int k  = t >> 4;
            int nq = (t & 15) * 4;
            const float4 bv = *(const float4*)(B + (long)(k0 + k) * N + bn + nq);
            Bs[k][nq + 0] = bv.x; Bs[k][nq + 1] = bv.y;
            Bs[k][nq + 2] = bv.z; Bs[k][nq + 3] = bv.w;
        }
        __syncthreads();
        #pragma unroll
        for (int k = 0; k < BKK; ++k) {
            float a[4], bb[4];
            #pragma unroll
            for (int i = 0; i < 4; ++i) a[i] = As[k][ty * 4 + i];
            #pragma unroll
            for (int j = 0; j < 4; ++j) bb[j] = Bs[k][tx * 4 + j];
            #pragma unroll
            for (int i = 0; i < 4; ++i)
                #pragma unroll
                for (int j = 0; j < 4; ++j)
                    acc[i][j] = fmaf(a[i], bb[j], acc[i][j]);
        }
        __syncthreads();
    }
    #pragma unroll
    for (int i = 0; i < 4; ++i) {
        const int row  = bm + ty * 4 + i;
        const int col0 = bn + tx * 4;
        #pragma unroll
        for (int j = 0; j < 4; ++j) {
            C[(long)row * N + col0 + j] = acc[i][j] + bias[col0 + j];
        }
    }
}

// ---------------- log_softmax over groups of 10 ----------------
__global__ __launch_bounds__(256) void log_softmax10(const float* __restrict__ logits,
                                                     float* __restrict__ out) {
    const int t = blockIdx.x * 256 + threadIdx.x;     // 64*512 groups
    if (t >= NB * L_DIM) return;
    const float* p = logits + (long)t * K_CLS;
    float v[K_CLS], m = -INFINITY;
    #pragma unroll
    for (int k = 0; k < K_CLS; ++k) { v[k] = p[k]; m = fmaxf(m, v[k]); }
    float s = 0.f;
    #pragma unroll
    for (int k = 0; k < K_CLS; ++k) s += __expf(v[k] - m);
    const float lse = m + logf(s);
    float* o = out + (long)t * K_CLS;
    #pragma unroll
    for (int k = 0; k < K_CLS; ++k) o[k] = v[k] - lse;
}

// ---------------- host launch ----------------
extern "C" void kernel_launch(void* const* d_in, const int* in_sizes, int n_in,
                              void* d_out, int out_size, void* d_ws, size_t ws_size,
                              hipStream_t stream) {
    const float* xs  = (const float*)d_in[0];
    const float* ys  = (const float*)d_in[1];
    const float* Wq1 = (const float*)d_in[2];  const float* bq1 = (const float*)d_in[3];
    const float* Wk1 = (const float*)d_in[4];  const float* bk1 = (const float*)d_in[5];
    const float* Wv1 = (const float*)d_in[6];  const float* bv1 = (const float*)d_in[7];
    const float* Wq2 = (const float*)d_in[8];  const float* bq2 = (const float*)d_in[9];
    const float* Wk2 = (const float*)d_in[10]; const float* bk2 = (const float*)d_in[11];
    const float* Wv2 = (const float*)d_in[12]; const float* bv2 = (const float*)d_in[13];
    const float* We  = (const float*)d_in[14]; const float* be  = (const float*)d_in[15];
    float* out = (float*)d_out;

    const long M  = (long)NB * S_LEN;        // 65536
    const long QL = M * L_DIM;               // 33.5M elems (== QL_ELEMS)
    const long SL = (long)S_LEN * L_DIM;     // per-batch activation stride (also V1T stride)
    const long SS = (long)S_LEN * S_LEN;     // per-batch score stride

    // ---- workspace layout (bf16 first, then fp32) ----
    bf16* Xb  = (bf16*)d_ws;                 // 33.5 MB
    bf16* B1  = Xb + M * D_IN;               // 67.1 MB  (q1 -> h)
    bf16* B2  = B1 + QL;                     // 67.1 MB  (k1 -> q2)
    bf16* B3  = B2 + QL;                     // 67.1 MB  (v1T -> k2)
    bf16* WTb = B3 + QL;                     // 1.8 MB: [Wq1T;Wk1T;Wv1T][Wq2T;Wk2T] contiguous
    bf16* Wq1T = WTb;                        // fused QKV1 B-matrix = WTb as [1536][256]
    bf16* Wk1T = Wq1T + L_DIM * D_IN;
    bf16* Wv1T = Wk1T + L_DIM * D_IN;
    bf16* Wq2T = Wv1T + L_DIM * D_IN;        // fused QK2 B-matrix = Wq2T as [1024][512]
    bf16* Wk2T = Wq2T + L_DIM * L_DIM;
    bf16* Scb  = Wk2T + L_DIM * L_DIM;       // BCH1 * 2 MB score chunk (layer-1 only)

    // L1 chunk = 16 batches -> 32MB Ptilde chunk, L3-resident (round-7/9 proven)
    const size_t base_b = (size_t)((char*)Scb - (char*)d_ws);
    const size_t f32_b  = (size_t)(NB * L_DIM + NB * L_DIM * K_CLS
                                   + 64 * 16 * 1024 + 4 * NB * L_DIM
                                   + 64 * 16 * 1024 + 1536 + 1024) * 4 + 256;
    int BCH1 = 16;
    while (BCH1 > 8 && base_b + (size_t)BCH1 * SS * 2 + f32_b > ws_size) BCH1 >>= 1;

    float* phi     = (float*)(Scb + (long)BCH1 * SS);
    float* lg      = phi + NB * L_DIM;
    float* ps      = lg  + NB * L_DIM * K_CLS;         // 16 row-sum partials x 64 batches
    float* up      = ps  + 64 * 16 * 1024;             // pool partials 64x4x512
    float* wps     = up  + 4 * NB * L_DIM;             // 16 col partials x 64 batches
    float* biasQKV = wps + 64 * 16 * 1024;             // 1536
    float* bias2   = biasQKV + 1536;                   // 1024

    const float inv_sqrt_L = 0.044194173824159216f;  // 1/sqrt(512)

    // 0) X build + weight transposes + bias concats, ONE dispatch
    {
        TW tw { xs, ys, Xb, Wq1, Wk1, Wv1, Wq2, Wk2, Wq1T, Wk1T, Wv1T, Wq2T, Wk2T,
                bq1, bk1, bv1, bq2, bk2, biasQKV, bias2 };
        prep_all<<<dim3((unsigned)((X_ELEMS + 920064 + 255) / 256)), 256, 0, stream>>>(tw);
    }

    // 1) layer-1 QKV fused (N=1536): q1->B1, k1->B2, v1T->B3 (seg2 transposed)
    {
        dim3 g(1536 / 128, S_LEN / 128, NB);
        gemm_mfma<false, true, false, false, true, 1, false><<<g, 256, 0, stream>>>(
            Xb, WTb, biasQKV, B1, D_IN, (long)S_LEN * D_IN, 0, SL, L_DIM, 1.f, nullptr, nullptr);
    }
    // 2) layer-1 attention, chunked (32MB L3-resident Ptilde chunk):
    //    Ptilde=exp(scores)+ps -> h = relu((P@v)/rowsum) -> B1  (rsinv inline from ps)
    for (int c = 0; c < NB / BCH1; ++c) {
        const long aoff = (long)c * BCH1 * SL;
        float* psc = ps + (long)c * BCH1 * 16 * 1024;
        dim3 gs(S_LEN / 128, S_LEN / 128, BCH1);
        gemm_mfma<false, false, true, false, true, 0, false><<<gs, 256, 0, stream>>>(
            B1 + aoff, B2 + aoff, nullptr, Scb, L_DIM, SL, SL, SS, S_LEN, inv_sqrt_L, psc, nullptr);
        dim3 gp(L_DIM / 128, S_LEN / 128, BCH1);
        gemm_mfma<true, false, false, true, true, 0, false><<<gp, 256, 0, stream>>>(
            Scb, B3 + aoff, nullptr, B1 + aoff, S_LEN, SS, SL, SL, L_DIM, 1.f, nullptr, psc);
    }
    // 3) layer-2 Q,K fused from h (B1): q2->B2, k2->B3 (v2 eliminated by linearity)
    {
        dim3 g(1024 / 128, S_LEN / 128, NB);
        gemm_mfma<false, true, false, false, true, 2, false><<<g, 256, 0, stream>>>(
            B1, Wq2T, bias2, B2, L_DIM, SL, 0, SL, L_DIM, 1.f, nullptr, nullptr);
    }
    // 4) layer-2 attention WITHOUT materializing Ptilde (round-9 proven):
    //    pass 1: row sums of exp(scores) (no C write);  pass 2: recompute scores,
    //    accumulate wps[col] partials of sum_q exp(s)/rowsum_q (rowsum inline).
    {
        dim3 gs(S_LEN / 128, S_LEN / 128, NB);
        gemm_mfma<false, false, true, false, false, 0, false><<<gs, 256, 0, stream>>>(
            B2, B3, nullptr, Scb, L_DIM, SL, SL, 0, S_LEN, inv_sqrt_L, ps, nullptr);
        gemm_mfma<false, false, false, false, false, 0, true><<<gs, 256, 0, stream>>>(
            B2, B3, nullptr, Scb, L_DIM, SL, SL, 0, S_LEN, inv_sqrt_L, wps, ps);
    }
    // 5) u-partials = (w-from-wps) @ h   (w inlined; 1/S applied in gemm_phi)
    pool_u_part<<<dim3(NB, 4), 256, 0, stream>>>(B1, wps, up);
    // 6) phi = relu((up-reduced/S) @ Wv2 + bv2)   (64 x 512, K=512)
    gemm_phi<<<dim3(L_DIM / TILE, 1), 256, 0, stream>>>(up, Wv2, bv2, phi);
    // 7) logits = phi @ We + be      (64 x 5120, K=512)
    gemm_f32s<<<dim3((L_DIM * K_CLS) / TILE, 1), 256, 0, stream>>>(phi, We, be, lg, NB, L_DIM * K_CLS, L_DIM);
    // 8) log_softmax over K=10
    log_softmax10<<<dim3((NB * L_DIM + 255) / 256), 256, 0, stream>>>(lg, out);
}